// Round 2
// baseline (1280.924 us; speedup 1.0000x reference)
//
#include <hip/hip_runtime.h>

#define NN      25000
#define TWO_N   50000
#define TT      8
#define CIN     32
#define ROWF    256      // TT*CIN floats per node row
#define COUT    64
#define FTOT    224
#define NEDGE   800000
#define WPAD    228      // FTOT padded: keeps 16B alignment per lane row, conflict-free
#define SCAN_BS 1024
#define NBLK    ((TWO_N + SCAN_BS - 1) / SCAN_BS)   // 49

// ---- CSR build ----
__global__ void hist_kernel(const int* __restrict__ dst, int* __restrict__ counts) {
    int i = blockIdx.x * blockDim.x + threadIdx.x;
    if (i < NEDGE) atomicAdd(&counts[dst[i]], 1);
}

// Two-level scan: per-block exclusive scan + block sums
__global__ void scan1_kernel(const int* __restrict__ counts, int* __restrict__ row_ptr,
                             int* __restrict__ bsums) {
    __shared__ int lds[SCAN_BS];
    int i = blockIdx.x * SCAN_BS + (int)threadIdx.x;
    int v = (i < TWO_N) ? counts[i] : 0;
    lds[threadIdx.x] = v;
    __syncthreads();
    for (int off = 1; off < SCAN_BS; off <<= 1) {
        int t = ((int)threadIdx.x >= off) ? lds[threadIdx.x - off] : 0;
        __syncthreads();
        lds[threadIdx.x] += t;
        __syncthreads();
    }
    if (i < TWO_N) row_ptr[i] = lds[threadIdx.x] - v;   // block-local exclusive
    if (threadIdx.x == SCAN_BS - 1) bsums[blockIdx.x] = lds[SCAN_BS - 1];
}

__global__ void scan2_kernel(int* __restrict__ bsums, int* __restrict__ row_ptr) {
    int lane = threadIdx.x;                 // one wave
    int orig = (lane < NBLK) ? bsums[lane] : 0;
    int v = orig;
    for (int off = 1; off < 64; off <<= 1) {
        int t = __shfl_up(v, off);
        if (lane >= off) v += t;
    }
    if (lane < NBLK) bsums[lane] = v - orig;     // exclusive block offsets
    if (lane == NBLK - 1) row_ptr[TWO_N] = v;    // grand total
}

__global__ void scan3_kernel(int* __restrict__ row_ptr, const int* __restrict__ bsums) {
    int i = blockIdx.x * SCAN_BS + (int)threadIdx.x;
    if (i < TWO_N) row_ptr[i] += bsums[blockIdx.x];
}

__global__ void scatter_kernel(const int* __restrict__ src, const int* __restrict__ dst,
                               const float* __restrict__ ef, const int* __restrict__ row_ptr,
                               int* __restrict__ fill, int* __restrict__ ssrc,
                               float* __restrict__ sef) {
    int i = blockIdx.x * blockDim.x + threadIdx.x;
    if (i < NEDGE) {
        int d = dst[i];
        int p = row_ptr[d] + atomicAdd(&fill[d], 1);
        ssrc[p] = src[i];
        sef[p]  = ef[i];
    }
}

// ---- SpMM: one wave per dst node; out[node] = scale*sum(ef*hin[src]) - sub[node'] ----
__global__ __launch_bounds__(256) void spmm_kernel(
        const int* __restrict__ row_ptr, const int* __restrict__ ssrc,
        const float* __restrict__ sef,
        const float* __restrict__ hin, int wrap_in,
        const float* __restrict__ sub, int wrap_sub,
        float scale, float* __restrict__ out) {
    int wid  = (int)((blockIdx.x * blockDim.x + threadIdx.x) >> 6);
    int lane = threadIdx.x & 63;
    if (wid >= TWO_N) return;
    int beg = row_ptr[wid], end = row_ptr[wid + 1];
    float4 a0 = make_float4(0.f, 0.f, 0.f, 0.f);
    float4 a1 = a0, a2 = a0, a3 = a0;
    int e = beg;
    for (; e + 4 <= end; e += 4) {
        int s0 = ssrc[e], s1 = ssrc[e + 1], s2 = ssrc[e + 2], s3 = ssrc[e + 3];
        float w0 = sef[e], w1 = sef[e + 1], w2 = sef[e + 2], w3 = sef[e + 3];
        if (wrap_in) {
            if (s0 >= NN) s0 -= NN;
            if (s1 >= NN) s1 -= NN;
            if (s2 >= NN) s2 -= NN;
            if (s3 >= NN) s3 -= NN;
        }
        float4 v0 = ((const float4*)(hin + (size_t)s0 * ROWF))[lane];
        float4 v1 = ((const float4*)(hin + (size_t)s1 * ROWF))[lane];
        float4 v2 = ((const float4*)(hin + (size_t)s2 * ROWF))[lane];
        float4 v3 = ((const float4*)(hin + (size_t)s3 * ROWF))[lane];
        a0.x = fmaf(w0, v0.x, a0.x); a0.y = fmaf(w0, v0.y, a0.y);
        a0.z = fmaf(w0, v0.z, a0.z); a0.w = fmaf(w0, v0.w, a0.w);
        a1.x = fmaf(w1, v1.x, a1.x); a1.y = fmaf(w1, v1.y, a1.y);
        a1.z = fmaf(w1, v1.z, a1.z); a1.w = fmaf(w1, v1.w, a1.w);
        a2.x = fmaf(w2, v2.x, a2.x); a2.y = fmaf(w2, v2.y, a2.y);
        a2.z = fmaf(w2, v2.z, a2.z); a2.w = fmaf(w2, v2.w, a2.w);
        a3.x = fmaf(w3, v3.x, a3.x); a3.y = fmaf(w3, v3.y, a3.y);
        a3.z = fmaf(w3, v3.z, a3.z); a3.w = fmaf(w3, v3.w, a3.w);
    }
    for (; e < end; ++e) {
        int s = ssrc[e];
        float w = sef[e];
        if (wrap_in && s >= NN) s -= NN;
        float4 v = ((const float4*)(hin + (size_t)s * ROWF))[lane];
        a0.x = fmaf(w, v.x, a0.x); a0.y = fmaf(w, v.y, a0.y);
        a0.z = fmaf(w, v.z, a0.z); a0.w = fmaf(w, v.w, a0.w);
    }
    float4 acc;
    acc.x = (a0.x + a1.x) + (a2.x + a3.x);
    acc.y = (a0.y + a1.y) + (a2.y + a3.y);
    acc.z = (a0.z + a1.z) + (a2.z + a3.z);
    acc.w = (a0.w + a1.w) + (a2.w + a3.w);
    float4 r;
    if (sub != nullptr) {
        int sn = wid;
        if (wrap_sub && sn >= NN) sn -= NN;
        float4 sv = ((const float4*)(sub + (size_t)sn * ROWF))[lane];
        r.x = scale * acc.x - sv.x;
        r.y = scale * acc.y - sv.y;
        r.z = scale * acc.z - sv.z;
        r.w = scale * acc.w - sv.w;
    } else {
        r = acc;
    }
    ((float4*)(out + (size_t)wid * ROWF))[lane] = r;
}

// ---- Output matmul: one wave per NODE (8 rows share W reads, 8x amortization).
// W transposed in LDS: WT[col][f], row pad 228 -> 16B-aligned float4 reads,
// bank pattern identical to contiguous access (conflict-free).
__global__ __launch_bounds__(512, 4) void out_kernel(
        const float* __restrict__ feat, const float* __restrict__ X1,
        const float* __restrict__ X2, const float* __restrict__ X3,
        const float* __restrict__ W, const float* __restrict__ b,
        float* __restrict__ out) {
    __shared__ float WT[COUT * WPAD];
    for (int i = threadIdx.x; i < FTOT * COUT; i += blockDim.x) {
        int f = i >> 6;          // 0..223
        int c = i & 63;          // 0..63
        WT[c * WPAD + f] = W[i];
    }
    __syncthreads();
    int lane = threadIdx.x & 63;
    int nwaves = (gridDim.x * blockDim.x) >> 6;
    int wid = (int)((blockIdx.x * blockDim.x + threadIdx.x) >> 6);
    float bias = b[lane];
    const float4* wrow = (const float4*)&WT[lane * WPAD];
    for (int node = wid; node < NN; node += nwaves) {
        size_t o_lo = (size_t)node * ROWF;
        size_t o_hi = (size_t)(node + NN) * ROWF;
        const float* ps[7] = { feat + o_lo, X1 + o_lo, X1 + o_hi,
                               X2 + o_lo, X2 + o_hi, X3 + o_lo, X3 + o_hi };
        float acc[TT];
        #pragma unroll
        for (int t = 0; t < TT; ++t) acc[t] = bias;
        #pragma unroll
        for (int a = 0; a < 7; ++a) {
            const float4* p = (const float4*)ps[a];   // [t][c4] = [8][8] float4
            #pragma unroll
            for (int c4 = 0; c4 < 8; ++c4) {
                float4 hv[TT];
                #pragma unroll
                for (int t = 0; t < TT; ++t) hv[t] = p[t * 8 + c4];
                float4 wv = wrow[a * 8 + c4];         // WT[lane][f..f+3]
                #pragma unroll
                for (int t = 0; t < TT; ++t) {
                    acc[t] = fmaf(hv[t].x, wv.x, acc[t]);
                    acc[t] = fmaf(hv[t].y, wv.y, acc[t]);
                    acc[t] = fmaf(hv[t].z, wv.z, acc[t]);
                    acc[t] = fmaf(hv[t].w, wv.w, acc[t]);
                }
            }
        }
        #pragma unroll
        for (int t = 0; t < TT; ++t)
            out[((size_t)node * TT + t) * COUT + lane] = acc[t];
    }
}

extern "C" void kernel_launch(void* const* d_in, const int* in_sizes, int n_in,
                              void* d_out, int out_size, void* d_ws, size_t ws_size,
                              hipStream_t stream) {
    const float* feat = (const float*)d_in[0];
    const float* ef   = (const float*)d_in[1];
    const float* W    = (const float*)d_in[2];
    const float* b    = (const float*)d_in[3];
    const int*   src  = (const int*)d_in[4];
    const int*   dst  = (const int*)d_in[5];
    float* out = (float*)d_out;

    // Workspace layout (~160.5 MB)
    float* X1 = (float*)d_ws;
    float* X2 = X1 + (size_t)TWO_N * ROWF;
    float* X3 = X2 + (size_t)TWO_N * ROWF;
    int* row_ptr = (int*)(X3 + (size_t)TWO_N * ROWF);
    int* counts  = row_ptr + TWO_N + 64;
    int* ssrc    = counts  + TWO_N + 64;
    float* sef   = (float*)(ssrc + NEDGE);
    int* bsums   = (int*)(sef + NEDGE);

    // CSR build (by dst)
    hipMemsetAsync(counts, 0, TWO_N * sizeof(int), stream);
    hist_kernel<<<(NEDGE + 255) / 256, 256, 0, stream>>>(dst, counts);
    scan1_kernel<<<NBLK, SCAN_BS, 0, stream>>>(counts, row_ptr, bsums);
    scan2_kernel<<<1, 64, 0, stream>>>(bsums, row_ptr);
    scan3_kernel<<<NBLK, SCAN_BS, 0, stream>>>(row_ptr, bsums);
    hipMemsetAsync(counts, 0, TWO_N * sizeof(int), stream);
    scatter_kernel<<<(NEDGE + 255) / 256, 256, 0, stream>>>(src, dst, ef, row_ptr,
                                                            counts, ssrc, sef);

    // Chebyshev diffusion steps
    int spmm_grid = (TWO_N + 3) / 4;   // 4 waves per 256-thread block
    spmm_kernel<<<spmm_grid, 256, 0, stream>>>(row_ptr, ssrc, sef,
                                               feat, 1, nullptr, 0, 1.0f, X1);
    spmm_kernel<<<spmm_grid, 256, 0, stream>>>(row_ptr, ssrc, sef,
                                               X1, 0, feat, 1, 2.0f, X2);
    spmm_kernel<<<spmm_grid, 256, 0, stream>>>(row_ptr, ssrc, sef,
                                               X2, 0, X1, 0, 2.0f, X3);

    // Output projection: one node per wave, 512 blocks x 8 waves
    out_kernel<<<512, 512, 0, stream>>>(feat, X1, X2, X3, W, b, out);
}

// Round 3
// 947.326 us; speedup vs baseline: 1.3521x; 1.3521x over previous
//
#include <hip/hip_runtime.h>

#define NN      25000
#define TWO_N   50000
#define TT      8
#define CIN     32
#define ROWF    256      // TT*CIN floats per node row
#define COUT    64
#define FTOT    224
#define NEDGE   800000
#define WPAD    228      // FTOT padded: lane stride 228 words -> 4-bank offset, ~free
#define SCAN_BS 1024
#define NBLK    ((TWO_N + SCAN_BS - 1) / SCAN_BS)   // 49

// ---- CSR build ----
__global__ void hist_kernel(const int* __restrict__ dst, int* __restrict__ counts) {
    int i = blockIdx.x * blockDim.x + threadIdx.x;
    if (i < NEDGE) atomicAdd(&counts[dst[i]], 1);
}

// Two-level scan: per-block exclusive scan + block sums
__global__ void scan1_kernel(const int* __restrict__ counts, int* __restrict__ row_ptr,
                             int* __restrict__ bsums) {
    __shared__ int lds[SCAN_BS];
    int i = blockIdx.x * SCAN_BS + (int)threadIdx.x;
    int v = (i < TWO_N) ? counts[i] : 0;
    lds[threadIdx.x] = v;
    __syncthreads();
    for (int off = 1; off < SCAN_BS; off <<= 1) {
        int t = ((int)threadIdx.x >= off) ? lds[threadIdx.x - off] : 0;
        __syncthreads();
        lds[threadIdx.x] += t;
        __syncthreads();
    }
    if (i < TWO_N) row_ptr[i] = lds[threadIdx.x] - v;   // block-local exclusive
    if (threadIdx.x == SCAN_BS - 1) bsums[blockIdx.x] = lds[SCAN_BS - 1];
}

__global__ void scan2_kernel(int* __restrict__ bsums, int* __restrict__ row_ptr) {
    int lane = threadIdx.x;                 // one wave
    int orig = (lane < NBLK) ? bsums[lane] : 0;
    int v = orig;
    for (int off = 1; off < 64; off <<= 1) {
        int t = __shfl_up(v, off);
        if (lane >= off) v += t;
    }
    if (lane < NBLK) bsums[lane] = v - orig;     // exclusive block offsets
    if (lane == NBLK - 1) row_ptr[TWO_N] = v;    // grand total
}

__global__ void scan3_kernel(int* __restrict__ row_ptr, const int* __restrict__ bsums) {
    int i = blockIdx.x * SCAN_BS + (int)threadIdx.x;
    if (i < TWO_N) row_ptr[i] += bsums[blockIdx.x];
}

__global__ void scatter_kernel(const int* __restrict__ src, const int* __restrict__ dst,
                               const float* __restrict__ ef, const int* __restrict__ row_ptr,
                               int* __restrict__ fill, int* __restrict__ ssrc,
                               float* __restrict__ sef) {
    int i = blockIdx.x * blockDim.x + threadIdx.x;
    if (i < NEDGE) {
        int d = dst[i];
        int p = row_ptr[d] + atomicAdd(&fill[d], 1);
        ssrc[p] = src[i];
        sef[p]  = ef[i];
    }
}

// ---- SpMM: one wave per dst node; out[node] = scale*sum(ef*hin[src]) - sub[node'] ----
__global__ __launch_bounds__(256) void spmm_kernel(
        const int* __restrict__ row_ptr, const int* __restrict__ ssrc,
        const float* __restrict__ sef,
        const float* __restrict__ hin, int wrap_in,
        const float* __restrict__ sub, int wrap_sub,
        float scale, float* __restrict__ out) {
    int wid  = (int)((blockIdx.x * blockDim.x + threadIdx.x) >> 6);
    int lane = threadIdx.x & 63;
    if (wid >= TWO_N) return;
    int beg = row_ptr[wid], end = row_ptr[wid + 1];
    float4 a0 = make_float4(0.f, 0.f, 0.f, 0.f);
    float4 a1 = a0, a2 = a0, a3 = a0;
    int e = beg;
    for (; e + 4 <= end; e += 4) {
        int s0 = ssrc[e], s1 = ssrc[e + 1], s2 = ssrc[e + 2], s3 = ssrc[e + 3];
        float w0 = sef[e], w1 = sef[e + 1], w2 = sef[e + 2], w3 = sef[e + 3];
        if (wrap_in) {
            if (s0 >= NN) s0 -= NN;
            if (s1 >= NN) s1 -= NN;
            if (s2 >= NN) s2 -= NN;
            if (s3 >= NN) s3 -= NN;
        }
        float4 v0 = ((const float4*)(hin + (size_t)s0 * ROWF))[lane];
        float4 v1 = ((const float4*)(hin + (size_t)s1 * ROWF))[lane];
        float4 v2 = ((const float4*)(hin + (size_t)s2 * ROWF))[lane];
        float4 v3 = ((const float4*)(hin + (size_t)s3 * ROWF))[lane];
        a0.x = fmaf(w0, v0.x, a0.x); a0.y = fmaf(w0, v0.y, a0.y);
        a0.z = fmaf(w0, v0.z, a0.z); a0.w = fmaf(w0, v0.w, a0.w);
        a1.x = fmaf(w1, v1.x, a1.x); a1.y = fmaf(w1, v1.y, a1.y);
        a1.z = fmaf(w1, v1.z, a1.z); a1.w = fmaf(w1, v1.w, a1.w);
        a2.x = fmaf(w2, v2.x, a2.x); a2.y = fmaf(w2, v2.y, a2.y);
        a2.z = fmaf(w2, v2.z, a2.z); a2.w = fmaf(w2, v2.w, a2.w);
        a3.x = fmaf(w3, v3.x, a3.x); a3.y = fmaf(w3, v3.y, a3.y);
        a3.z = fmaf(w3, v3.z, a3.z); a3.w = fmaf(w3, v3.w, a3.w);
    }
    for (; e < end; ++e) {
        int s = ssrc[e];
        float w = sef[e];
        if (wrap_in && s >= NN) s -= NN;
        float4 v = ((const float4*)(hin + (size_t)s * ROWF))[lane];
        a0.x = fmaf(w, v.x, a0.x); a0.y = fmaf(w, v.y, a0.y);
        a0.z = fmaf(w, v.z, a0.z); a0.w = fmaf(w, v.w, a0.w);
    }
    float4 acc;
    acc.x = (a0.x + a1.x) + (a2.x + a3.x);
    acc.y = (a0.y + a1.y) + (a2.y + a3.y);
    acc.z = (a0.z + a1.z) + (a2.z + a3.z);
    acc.w = (a0.w + a1.w) + (a2.w + a3.w);
    float4 r;
    if (sub != nullptr) {
        int sn = wid;
        if (wrap_sub && sn >= NN) sn -= NN;
        float4 sv = ((const float4*)(sub + (size_t)sn * ROWF))[lane];
        r.x = scale * acc.x - sv.x;
        r.y = scale * acc.y - sv.y;
        r.z = scale * acc.z - sv.z;
        r.w = scale * acc.w - sv.w;
    } else {
        r = acc;
    }
    ((float4*)(out + (size_t)wid * ROWF))[lane] = r;
}

// ---- Output matmul: one wave per NODE; W column per lane in LDS (transposed).
// Inner order: wv (1x ds_read_b128, reused 8x over t) -> stream hv one at a time.
// Live regs ~ acc[8] + wv + few hv in flight: no spills.
__global__ __launch_bounds__(512, 2) void out_kernel(
        const float* __restrict__ feat, const float* __restrict__ X1,
        const float* __restrict__ X2, const float* __restrict__ X3,
        const float* __restrict__ W, const float* __restrict__ b,
        float* __restrict__ out) {
    __shared__ float WT[COUT * WPAD];
    for (int i = threadIdx.x; i < FTOT * COUT; i += blockDim.x) {
        int f = i >> 6;          // 0..223
        int c = i & 63;          // 0..63
        WT[c * WPAD + f] = W[i];
    }
    __syncthreads();
    int lane = threadIdx.x & 63;
    int nwaves = (gridDim.x * blockDim.x) >> 6;
    int wid = (int)((blockIdx.x * blockDim.x + threadIdx.x) >> 6);
    float bias = b[lane];
    const float4* wrow = (const float4*)&WT[lane * WPAD];
    for (int node = wid; node < NN; node += nwaves) {
        size_t o_lo = (size_t)node * ROWF;
        size_t o_hi = (size_t)(node + NN) * ROWF;
        const float* ps[7] = { feat + o_lo, X1 + o_lo, X1 + o_hi,
                               X2 + o_lo, X2 + o_hi, X3 + o_lo, X3 + o_hi };
        float acc[TT];
        #pragma unroll
        for (int t = 0; t < TT; ++t) acc[t] = bias;
        #pragma unroll
        for (int a = 0; a < 7; ++a) {
            const float4* p = (const float4*)ps[a];   // [t][c4] = [8][8] float4
            #pragma unroll
            for (int c4 = 0; c4 < 8; ++c4) {
                float4 wv = wrow[a * 8 + c4];         // WT[lane][f..f+3]
                #pragma unroll
                for (int t = 0; t < TT; ++t) {
                    float4 hv = p[t * 8 + c4];
                    acc[t] = fmaf(hv.x, wv.x, acc[t]);
                    acc[t] = fmaf(hv.y, wv.y, acc[t]);
                    acc[t] = fmaf(hv.z, wv.z, acc[t]);
                    acc[t] = fmaf(hv.w, wv.w, acc[t]);
                }
            }
        }
        #pragma unroll
        for (int t = 0; t < TT; ++t)
            out[((size_t)node * TT + t) * COUT + lane] = acc[t];
    }
}

extern "C" void kernel_launch(void* const* d_in, const int* in_sizes, int n_in,
                              void* d_out, int out_size, void* d_ws, size_t ws_size,
                              hipStream_t stream) {
    const float* feat = (const float*)d_in[0];
    const float* ef   = (const float*)d_in[1];
    const float* W    = (const float*)d_in[2];
    const float* b    = (const float*)d_in[3];
    const int*   src  = (const int*)d_in[4];
    const int*   dst  = (const int*)d_in[5];
    float* out = (float*)d_out;

    // Workspace layout (~160.5 MB)
    float* X1 = (float*)d_ws;
    float* X2 = X1 + (size_t)TWO_N * ROWF;
    float* X3 = X2 + (size_t)TWO_N * ROWF;
    int* row_ptr = (int*)(X3 + (size_t)TWO_N * ROWF);
    int* counts  = row_ptr + TWO_N + 64;
    int* ssrc    = counts  + TWO_N + 64;
    float* sef   = (float*)(ssrc + NEDGE);
    int* bsums   = (int*)(sef + NEDGE);

    // CSR build (by dst)
    hipMemsetAsync(counts, 0, TWO_N * sizeof(int), stream);
    hist_kernel<<<(NEDGE + 255) / 256, 256, 0, stream>>>(dst, counts);
    scan1_kernel<<<NBLK, SCAN_BS, 0, stream>>>(counts, row_ptr, bsums);
    scan2_kernel<<<1, 64, 0, stream>>>(bsums, row_ptr);
    scan3_kernel<<<NBLK, SCAN_BS, 0, stream>>>(row_ptr, bsums);
    hipMemsetAsync(counts, 0, TWO_N * sizeof(int), stream);
    scatter_kernel<<<(NEDGE + 255) / 256, 256, 0, stream>>>(src, dst, ef, row_ptr,
                                                            counts, ssrc, sef);

    // Chebyshev diffusion steps
    int spmm_grid = (TWO_N + 3) / 4;   // 4 waves per 256-thread block
    spmm_kernel<<<spmm_grid, 256, 0, stream>>>(row_ptr, ssrc, sef,
                                               feat, 1, nullptr, 0, 1.0f, X1);
    spmm_kernel<<<spmm_grid, 256, 0, stream>>>(row_ptr, ssrc, sef,
                                               X1, 0, feat, 1, 2.0f, X2);
    spmm_kernel<<<spmm_grid, 256, 0, stream>>>(row_ptr, ssrc, sef,
                                               X2, 0, X1, 0, 2.0f, X3);

    // Output projection: one node per wave, 512 blocks x 8 waves
    out_kernel<<<512, 512, 0, stream>>>(feat, X1, X2, X3, W, b, out);
}

// Round 4
// 590.266 us; speedup vs baseline: 2.1701x; 1.6049x over previous
//
#include <hip/hip_runtime.h>

#define NN      25000
#define TWO_N   50000
#define TT      8
#define CIN     32
#define ROWF    256      // TT*CIN floats per node row
#define COUT    64
#define FTOT    224
#define NEDGE   800000
#define WPAD    228      // pad: lane stride 228 words -> minimal-conflict b128 pattern
#define SCAN_BS 1024
#define NBLK    ((TWO_N + SCAN_BS - 1) / SCAN_BS)   // 49

// ---- CSR build ----
__global__ void hist_kernel(const int* __restrict__ dst, int* __restrict__ counts) {
    int i = blockIdx.x * blockDim.x + threadIdx.x;
    if (i < NEDGE) atomicAdd(&counts[dst[i]], 1);
}

// Two-level scan: per-block exclusive scan + block sums
__global__ void scan1_kernel(const int* __restrict__ counts, int* __restrict__ row_ptr,
                             int* __restrict__ bsums) {
    __shared__ int lds[SCAN_BS];
    int i = blockIdx.x * SCAN_BS + (int)threadIdx.x;
    int v = (i < TWO_N) ? counts[i] : 0;
    lds[threadIdx.x] = v;
    __syncthreads();
    for (int off = 1; off < SCAN_BS; off <<= 1) {
        int t = ((int)threadIdx.x >= off) ? lds[threadIdx.x - off] : 0;
        __syncthreads();
        lds[threadIdx.x] += t;
        __syncthreads();
    }
    if (i < TWO_N) row_ptr[i] = lds[threadIdx.x] - v;   // block-local exclusive
    if (threadIdx.x == SCAN_BS - 1) bsums[blockIdx.x] = lds[SCAN_BS - 1];
}

__global__ void scan2_kernel(int* __restrict__ bsums, int* __restrict__ row_ptr) {
    int lane = threadIdx.x;                 // one wave
    int orig = (lane < NBLK) ? bsums[lane] : 0;
    int v = orig;
    for (int off = 1; off < 64; off <<= 1) {
        int t = __shfl_up(v, off);
        if (lane >= off) v += t;
    }
    if (lane < NBLK) bsums[lane] = v - orig;     // exclusive block offsets
    if (lane == NBLK - 1) row_ptr[TWO_N] = v;    // grand total
}

__global__ void scan3_kernel(int* __restrict__ row_ptr, const int* __restrict__ bsums) {
    int i = blockIdx.x * SCAN_BS + (int)threadIdx.x;
    if (i < TWO_N) row_ptr[i] += bsums[blockIdx.x];
}

__global__ void scatter_kernel(const int* __restrict__ src, const int* __restrict__ dst,
                               const float* __restrict__ ef, const int* __restrict__ row_ptr,
                               int* __restrict__ fill, int* __restrict__ ssrc,
                               float* __restrict__ sef) {
    int i = blockIdx.x * blockDim.x + threadIdx.x;
    if (i < NEDGE) {
        int d = dst[i];
        int p = row_ptr[d] + atomicAdd(&fill[d], 1);
        ssrc[p] = src[i];
        sef[p]  = ef[i];
    }
}

// ---- SpMM: one wave per dst node; out[node] = scale*sum(ef*hin[src]) - sub[node'] ----
__global__ __launch_bounds__(256) void spmm_kernel(
        const int* __restrict__ row_ptr, const int* __restrict__ ssrc,
        const float* __restrict__ sef,
        const float* __restrict__ hin, int wrap_in,
        const float* __restrict__ sub, int wrap_sub,
        float scale, float* __restrict__ out) {
    int wid  = (int)((blockIdx.x * blockDim.x + threadIdx.x) >> 6);
    int lane = threadIdx.x & 63;
    if (wid >= TWO_N) return;
    int beg = row_ptr[wid], end = row_ptr[wid + 1];
    float4 a0 = make_float4(0.f, 0.f, 0.f, 0.f);
    float4 a1 = a0, a2 = a0, a3 = a0;
    int e = beg;
    for (; e + 4 <= end; e += 4) {
        int s0 = ssrc[e], s1 = ssrc[e + 1], s2 = ssrc[e + 2], s3 = ssrc[e + 3];
        float w0 = sef[e], w1 = sef[e + 1], w2 = sef[e + 2], w3 = sef[e + 3];
        if (wrap_in) {
            if (s0 >= NN) s0 -= NN;
            if (s1 >= NN) s1 -= NN;
            if (s2 >= NN) s2 -= NN;
            if (s3 >= NN) s3 -= NN;
        }
        float4 v0 = ((const float4*)(hin + (size_t)s0 * ROWF))[lane];
        float4 v1 = ((const float4*)(hin + (size_t)s1 * ROWF))[lane];
        float4 v2 = ((const float4*)(hin + (size_t)s2 * ROWF))[lane];
        float4 v3 = ((const float4*)(hin + (size_t)s3 * ROWF))[lane];
        a0.x = fmaf(w0, v0.x, a0.x); a0.y = fmaf(w0, v0.y, a0.y);
        a0.z = fmaf(w0, v0.z, a0.z); a0.w = fmaf(w0, v0.w, a0.w);
        a1.x = fmaf(w1, v1.x, a1.x); a1.y = fmaf(w1, v1.y, a1.y);
        a1.z = fmaf(w1, v1.z, a1.z); a1.w = fmaf(w1, v1.w, a1.w);
        a2.x = fmaf(w2, v2.x, a2.x); a2.y = fmaf(w2, v2.y, a2.y);
        a2.z = fmaf(w2, v2.z, a2.z); a2.w = fmaf(w2, v2.w, a2.w);
        a3.x = fmaf(w3, v3.x, a3.x); a3.y = fmaf(w3, v3.y, a3.y);
        a3.z = fmaf(w3, v3.z, a3.z); a3.w = fmaf(w3, v3.w, a3.w);
    }
    for (; e < end; ++e) {
        int s = ssrc[e];
        float w = sef[e];
        if (wrap_in && s >= NN) s -= NN;
        float4 v = ((const float4*)(hin + (size_t)s * ROWF))[lane];
        a0.x = fmaf(w, v.x, a0.x); a0.y = fmaf(w, v.y, a0.y);
        a0.z = fmaf(w, v.z, a0.z); a0.w = fmaf(w, v.w, a0.w);
    }
    float4 acc;
    acc.x = (a0.x + a1.x) + (a2.x + a3.x);
    acc.y = (a0.y + a1.y) + (a2.y + a3.y);
    acc.z = (a0.z + a1.z) + (a2.z + a3.z);
    acc.w = (a0.w + a1.w) + (a2.w + a3.w);
    float4 r;
    if (sub != nullptr) {
        int sn = wid;
        if (wrap_sub && sn >= NN) sn -= NN;
        float4 sv = ((const float4*)(sub + (size_t)sn * ROWF))[lane];
        r.x = scale * acc.x - sv.x;
        r.y = scale * acc.y - sv.y;
        r.z = scale * acc.z - sv.z;
        r.w = scale * acc.w - sv.w;
    } else {
        r = acc;
    }
    ((float4*)(out + (size_t)wid * ROWF))[lane] = r;
}

// ---- Output matmul: one wave per NODE.
// Cooperative coalesced loads: each source array's 256-float node-row is exactly
// one wave-level float4 load (lane L -> t=L>>3, f=(L&7)*4). Redistribute through a
// per-wave PRIVATE LDS tile (no barrier; same-wave write->read). h reads in the FMA
// loop are wave-broadcast ds_read_b128 (conflict-free); W column reads are
// lane-strided b128 on a 228-word pitch (minimal 8-slot bank pattern).
// Next node's 7 loads are prefetched under the current node's 1792 FMAs.
__global__ __launch_bounds__(512) void out_kernel(
        const float* __restrict__ feat, const float* __restrict__ X1,
        const float* __restrict__ X2, const float* __restrict__ X3,
        const float* __restrict__ W, const float* __restrict__ b,
        float* __restrict__ out) {
    __shared__ float WT[COUT * WPAD];          // 58368 B
    __shared__ float Ht[8][TT * WPAD];         // 8 waves x 7296 B = 58368 B
    for (int i = threadIdx.x; i < FTOT * COUT; i += blockDim.x) {
        int f = i >> 6;          // 0..223
        int c = i & 63;          // 0..63
        WT[c * WPAD + f] = W[i];
    }
    __syncthreads();

    int lane = threadIdx.x & 63;
    int w    = threadIdx.x >> 6;
    float* ht = Ht[w];
    int lt  = lane >> 3;         // t this lane loads
    int lf4 = lane & 7;          // f4-within-array this lane loads
    int nwaves = (gridDim.x * blockDim.x) >> 6;
    int wid = (int)((blockIdx.x * blockDim.x + threadIdx.x) >> 6);
    float bias = b[lane];
    const float4* wrow = (const float4*)&WT[lane * WPAD];

    // prefetch first node
    float4 r[7];
    int node = wid;
    if (node < NN) {
        size_t o_lo = (size_t)node * ROWF;
        size_t o_hi = (size_t)(node + NN) * ROWF;
        const float* ps[7] = { feat + o_lo, X1 + o_lo, X1 + o_hi,
                               X2 + o_lo, X2 + o_hi, X3 + o_lo, X3 + o_hi };
        #pragma unroll
        for (int a = 0; a < 7; ++a) r[a] = ((const float4*)ps[a])[lane];
    }

    for (; node < NN; node += nwaves) {
        // stage current node's h into this wave's private LDS tile
        #pragma unroll
        for (int a = 0; a < 7; ++a)
            *(float4*)&ht[lt * WPAD + a * CIN + lf4 * 4] = r[a];

        // prefetch next node while computing
        int node2 = node + nwaves;
        if (node2 < NN) {
            size_t o_lo = (size_t)node2 * ROWF;
            size_t o_hi = (size_t)(node2 + NN) * ROWF;
            const float* ps[7] = { feat + o_lo, X1 + o_lo, X1 + o_hi,
                                   X2 + o_lo, X2 + o_hi, X3 + o_lo, X3 + o_hi };
            #pragma unroll
            for (int a = 0; a < 7; ++a) r[a] = ((const float4*)ps[a])[lane];
        }

        float acc[TT];
        #pragma unroll
        for (int t = 0; t < TT; ++t) acc[t] = bias;
        #pragma unroll
        for (int f4 = 0; f4 < FTOT / 4; ++f4) {
            float4 wv = wrow[f4];                      // W[f..f+3][lane]
            #pragma unroll
            for (int t = 0; t < TT; ++t) {
                float4 hv = *(const float4*)&ht[t * WPAD + f4 * 4];  // broadcast
                acc[t] = fmaf(hv.x, wv.x, acc[t]);
                acc[t] = fmaf(hv.y, wv.y, acc[t]);
                acc[t] = fmaf(hv.z, wv.z, acc[t]);
                acc[t] = fmaf(hv.w, wv.w, acc[t]);
            }
        }
        #pragma unroll
        for (int t = 0; t < TT; ++t)
            out[(size_t)node * (TT * COUT) + t * COUT + lane] = acc[t];
    }
}

extern "C" void kernel_launch(void* const* d_in, const int* in_sizes, int n_in,
                              void* d_out, int out_size, void* d_ws, size_t ws_size,
                              hipStream_t stream) {
    const float* feat = (const float*)d_in[0];
    const float* ef   = (const float*)d_in[1];
    const float* W    = (const float*)d_in[2];
    const float* b    = (const float*)d_in[3];
    const int*   src  = (const int*)d_in[4];
    const int*   dst  = (const int*)d_in[5];
    float* out = (float*)d_out;

    // Workspace layout (~160.5 MB)
    float* X1 = (float*)d_ws;
    float* X2 = X1 + (size_t)TWO_N * ROWF;
    float* X3 = X2 + (size_t)TWO_N * ROWF;
    int* row_ptr = (int*)(X3 + (size_t)TWO_N * ROWF);
    int* counts  = row_ptr + TWO_N + 64;
    int* ssrc    = counts  + TWO_N + 64;
    float* sef   = (float*)(ssrc + NEDGE);
    int* bsums   = (int*)(sef + NEDGE);

    // CSR build (by dst)
    hipMemsetAsync(counts, 0, TWO_N * sizeof(int), stream);
    hist_kernel<<<(NEDGE + 255) / 256, 256, 0, stream>>>(dst, counts);
    scan1_kernel<<<NBLK, SCAN_BS, 0, stream>>>(counts, row_ptr, bsums);
    scan2_kernel<<<1, 64, 0, stream>>>(bsums, row_ptr);
    scan3_kernel<<<NBLK, SCAN_BS, 0, stream>>>(row_ptr, bsums);
    hipMemsetAsync(counts, 0, TWO_N * sizeof(int), stream);
    scatter_kernel<<<(NEDGE + 255) / 256, 256, 0, stream>>>(src, dst, ef, row_ptr,
                                                            counts, ssrc, sef);

    // Chebyshev diffusion steps
    int spmm_grid = (TWO_N + 3) / 4;   // 4 waves per 256-thread block
    spmm_kernel<<<spmm_grid, 256, 0, stream>>>(row_ptr, ssrc, sef,
                                               feat, 1, nullptr, 0, 1.0f, X1);
    spmm_kernel<<<spmm_grid, 256, 0, stream>>>(row_ptr, ssrc, sef,
                                               X1, 0, feat, 1, 2.0f, X2);
    spmm_kernel<<<spmm_grid, 256, 0, stream>>>(row_ptr, ssrc, sef,
                                               X2, 0, X1, 0, 2.0f, X3);

    // Output projection: one node per wave; 256 blocks x 8 waves (1 block/CU, LDS-bound)
    out_kernel<<<256, 512, 0, stream>>>(feat, X1, X2, X3, W, b, out);
}